// Round 10
// baseline (147.155 us; speedup 1.0000x reference)
//
#include <hip/hip_runtime.h>

// AttentionLayer: B=2,T=12,N=1024,D=128,H=8,HD=16
// R10 = R9 + attn 2-q-tile waves: each wave owns 32 q-rows; K/V LDS fragments
// read once per 32-j window and applied to both Q fragments (halves LDS-pipe
// load and K/V global refetch; exp2 total invariant).
// attn: S^T = K*Q via mfma 16x16x16; K row-permutation folded into the LDS
//   read base. S^T C-layout == 16x16x32 A-frag layout, so PV + denominator
//   are single x32 MFMAs per 32 j per tile (denominator = all-ones B).
// qkv_proj: q/k via LDS-transpose -> coalesced b128; v transposed [bt][h][hd][n].
// softmax scale 1/4*log2(e) folded into stored q (raw exp2 path).

#define DEV __device__ __forceinline__

typedef __attribute__((ext_vector_type(4))) float f32x4;
typedef __attribute__((ext_vector_type(8))) short s16x8;
typedef __attribute__((ext_vector_type(4))) short s16x4;
typedef __attribute__((ext_vector_type(2))) unsigned int u32x2;
typedef __attribute__((ext_vector_type(4))) unsigned int u32x4;

DEV unsigned short f2bf(float f) {          // fp32 -> bf16, round-nearest-even
    unsigned u = __builtin_bit_cast(unsigned, f);
    u = (u + 0x7fffu + ((u >> 16) & 1u)) >> 16;
    return (unsigned short)u;
}

DEV unsigned pack_bf16(float a, float b) {  // {lo=bf16(a), hi=bf16(b)}
#if __has_builtin(__builtin_amdgcn_cvt_pk_bf16_f32)
    typedef __attribute__((ext_vector_type(2))) __bf16 bf16x2;
    bf16x2 t = __builtin_amdgcn_cvt_pk_bf16_f32(a, b);
    return __builtin_bit_cast(unsigned, t);
#else
    // round-half-up: 3 VALU ops; bias cancels in softmax ratio (R4-R9: absmax ok)
    unsigned ua = __builtin_bit_cast(unsigned, a) + 0x8000u;
    unsigned ub = __builtin_bit_cast(unsigned, b) + 0x8000u;
    return __builtin_amdgcn_perm(ub, ua, 0x07060302);  // {ub.hi16, ua.hi16}
#endif
}

DEV f32x4 mfma16(s16x4 a, s16x4 b, f32x4 c) {
#if __has_builtin(__builtin_amdgcn_mfma_f32_16x16x16bf16_1k)
    return __builtin_amdgcn_mfma_f32_16x16x16bf16_1k(a, b, c, 0, 0, 0);
#else
    s16x8 a8 = {a[0], a[1], a[2], a[3], 0, 0, 0, 0};
    s16x8 b8 = {b[0], b[1], b[2], b[3], 0, 0, 0, 0};
    return __builtin_amdgcn_mfma_f32_16x16x32_bf16(a8, b8, c, 0, 0, 0);
#endif
}

DEV f32x4 mfma32(s16x8 a, s16x8 b, f32x4 c) {
    return __builtin_amdgcn_mfma_f32_16x16x32_bf16(a, b, c, 0, 0, 0);
}

// ---------------------------------------------------------------- qkv proj ---
// grid (384, 3): x = 64-row tile of M=24576, y = which of q/k/v.
__global__ __launch_bounds__(256)
void qkv_proj_kernel(const float* __restrict__ xq, const float* __restrict__ xk,
                     const float* __restrict__ xv,
                     const float* __restrict__ Wq, const float* __restrict__ Wk,
                     const float* __restrict__ Wv,
                     const float* __restrict__ bq, const float* __restrict__ bk,
                     const float* __restrict__ bv,
                     unsigned short* __restrict__ oq, unsigned short* __restrict__ ok,
                     unsigned short* __restrict__ ov)
{
    const int z = blockIdx.y;
    const float* X    = (z == 0) ? xq : (z == 1) ? xk : xv;
    const float* W    = (z == 0) ? Wq : (z == 1) ? Wk : Wv;
    const float* bias = (z == 0) ? bq : (z == 1) ? bk : bv;
    unsigned short* out = (z == 0) ? oq : (z == 1) ? ok : ov;
    const float scale = (z == 0) ? 0.25f * 1.44269504088896f : 1.0f;

    __shared__ unsigned short Xs[64 * 136];
    __shared__ unsigned short Ws[128 * 136];

    const int t  = threadIdx.x;
    const int m0 = blockIdx.x * 64;

    {
        const float4* Xg = (const float4*)(X + (size_t)m0 * 128);
        #pragma unroll
        for (int p = 0; p < 8; p++) {
            int g = p * 256 + t;
            float4 vv = Xg[g];
            int row = g >> 5, c4 = g & 31;
            ushort4 d;
            d.x = f2bf(vv.x); d.y = f2bf(vv.y); d.z = f2bf(vv.z); d.w = f2bf(vv.w);
            *(ushort4*)&Xs[row * 136 + c4 * 4] = d;
        }
        const float4* Wg = (const float4*)W;
        #pragma unroll
        for (int p = 0; p < 16; p++) {
            int g = p * 256 + t;
            float4 vv = Wg[g];
            int row = g >> 5, c4 = g & 31;
            ushort4 d;
            d.x = f2bf(vv.x); d.y = f2bf(vv.y); d.z = f2bf(vv.z); d.w = f2bf(vv.w);
            *(ushort4*)&Ws[row * 136 + c4 * 4] = d;
        }
    }
    __syncthreads();

    const int wave = t >> 6, lane = t & 63, quad = lane >> 4, n16 = lane & 15;
    f32x4 acc[8];
    const f32x4 zero4 = {0.f, 0.f, 0.f, 0.f};
    #pragma unroll
    for (int i = 0; i < 8; i++) acc[i] = zero4;

    #pragma unroll
    for (int ks = 0; ks < 4; ks++) {
        s16x8 a = *(const s16x8*)&Xs[(wave * 16 + n16) * 136 + ks * 32 + quad * 8];
        #pragma unroll
        for (int nt = 0; nt < 8; nt++) {
            s16x8 b = *(const s16x8*)&Ws[(nt * 16 + n16) * 136 + ks * 32 + quad * 8];
            acc[nt] = __builtin_amdgcn_mfma_f32_16x16x32_bf16(a, b, acc[nt], 0, 0, 0);
        }
    }

    const int bt    = m0 >> 10;
    const int nbase = (m0 & 1023) + wave * 16 + quad * 4;
    if (z == 2) {
        // V transposed [bt][h][hd][n]: lane holds 4 consecutive n for hd=n16
        #pragma unroll
        for (int nt = 0; nt < 8; nt++) {
            float bb = bias[nt * 16 + n16];
            u32x2 pv = {pack_bf16(acc[nt][0] + bb, acc[nt][1] + bb),
                        pack_bf16(acc[nt][2] + bb, acc[nt][3] + bb)};
            *(u32x2*)&out[((size_t)(bt * 8 + nt) * 16 + n16) * 1024 + nbase] = pv;
        }
    } else {
        // q/k [bt][h][n][hd]: transpose through Xs (done with it) -> coalesced stores
        __syncthreads();
        const int crow = wave * 16 + quad * 4;
        #pragma unroll
        for (int nt = 0; nt < 8; nt++) {
            float bb = bias[nt * 16 + n16];
            #pragma unroll
            for (int r = 0; r < 4; r++)
                Xs[(crow + r) * 136 + nt * 16 + n16] = f2bf((acc[nt][r] + bb) * scale);
        }
        __syncthreads();
        #pragma unroll
        for (int p = 0; p < 4; p++) {
            int g = p * 256 + t, row = g >> 4, ch = g & 15;   // ch*8 = h*16 + seg
            s16x8 val = *(const s16x8*)&Xs[row * 136 + ch * 8];
            *(s16x8*)&out[((size_t)(bt * 8 + (ch >> 1)) * 1024 + (m0 & 1023) + row) * 16
                          + (ch & 1) * 8] = val;
        }
    }
}

// ---------------------------------------------------------------- attention ---
// grid (8, 8, 24): x = 128-row q block, y = head, z = bt.  4 waves; each wave
// owns TWO 16-row q-tiles (q0, q0+16) and amortizes K/V LDS reads over both.
// 128-j chunks, double-buffered; 18.9 KB LDS.
__global__ __launch_bounds__(256)
void attn_kernel(const unsigned short* __restrict__ q,
                 const unsigned short* __restrict__ k,
                 const unsigned short* __restrict__ vt,
                 unsigned short* __restrict__ O)
{
    __shared__ unsigned short Ks[2][128 * 20];   // K chunk [j][hd], stride 20
    __shared__ unsigned short VTs[2][16 * 136];  // V^T chunk [hd][j], stride 136

    const int t    = threadIdx.x;
    const int lane = t & 63, quad = lane >> 4, n16 = lane & 15;
    const int wave = t >> 6;
    const int bx = blockIdx.x, h = blockIdx.y, bt = blockIdx.z;
    const size_t headoff = (size_t)(bt * 8 + h) * 16384;
    const int q0 = bx * 128 + wave * 32;         // two tiles: q0, q0+16

    // Q B-frags (loop-invariant): B[n=q][k=hd], lane n16 holds hd = quad*4..+3
    s16x4 qfA = *(const s16x4*)(q + headoff + (size_t)(q0 + n16) * 16 + quad * 4);
    s16x4 qfB = *(const s16x4*)(q + headoff + (size_t)(q0 + 16 + n16) * 16 + quad * 4);

    const f32x4 zero4 = {0.f, 0.f, 0.f, 0.f};
    f32x4 oaccA = zero4, daccA = zero4, oaccB = zero4, daccB = zero4;
    const s16x8 ones = {0x3F80, 0x3F80, 0x3F80, 0x3F80,
                        0x3F80, 0x3F80, 0x3F80, 0x3F80};   // bf16 1.0 x8
    // tile0 lane row j = 8*(n16>>2) + (n16&3)  (permutation folded into base)
    const int krd0 = (8 * (n16 >> 2) + (n16 & 3)) * 20 + quad * 4;
    const int vrd  = n16 * 136 + quad * 8;
    // staging assignments (straight copies)
    const int krow = t >> 2, kseg = (t & 3) * 4;   // K: 2 iters x (64 rows, b64)
    const int vrow = t >> 4, vseg = (t & 15) * 8;  // V: 1 iter  (16 rows, b128)
    const unsigned short* kg = k  + headoff + (size_t)krow * 16 + kseg;
    const unsigned short* vg = vt + headoff + (size_t)vrow * 1024 + vseg;

    // prologue: stage chunk 0 into buffer 0
    #pragma unroll
    for (int p = 0; p < 2; p++)
        *(s16x4*)&Ks[0][(p * 64 + krow) * 20 + kseg] =
            *(const s16x4*)(kg + (size_t)p * 1024);
    *(s16x8*)&VTs[0][vrow * 136 + vseg] = *(const s16x8*)vg;

    #pragma unroll
    for (int c = 0; c < 8; c++) {                 // 8 chunks of 128 j
        __syncthreads();                          // buf[c&1] ready; other free
        s16x4 kst[2];
        s16x8 vst;
        if (c < 7) {                              // issue next chunk's loads now
            #pragma unroll
            for (int p = 0; p < 2; p++)
                kst[p] = *(const s16x4*)(kg + (size_t)((c + 1) * 128 + p * 64) * 16);
            vst = *(const s16x8*)(vg + (c + 1) * 128);
        }
        const unsigned short* Kc = Ks[c & 1];
        const unsigned short* Vc = VTs[c & 1];
        #pragma unroll
        for (int w = 0; w < 4; w++) {             // 4 windows of 32 j
            s16x4 kf0 = *(const s16x4*)&Kc[w * 640 + krd0];        // j=8a+r
            s16x4 kf1 = *(const s16x4*)&Kc[w * 640 + krd0 + 80];   // j=8a+4+r
            s16x8 vf  = *(const s16x8*)&Vc[w * 32 + vrd];
            // tile A
            f32x4 s0 = mfma16(kf0, qfA, zero4);
            f32x4 s1 = mfma16(kf1, qfA, zero4);
            float a0 = __builtin_amdgcn_exp2f(s0[0]);
            float a1 = __builtin_amdgcn_exp2f(s0[1]);
            float a2 = __builtin_amdgcn_exp2f(s0[2]);
            float a3 = __builtin_amdgcn_exp2f(s0[3]);
            float a4 = __builtin_amdgcn_exp2f(s1[0]);
            float a5 = __builtin_amdgcn_exp2f(s1[1]);
            float a6 = __builtin_amdgcn_exp2f(s1[2]);
            float a7 = __builtin_amdgcn_exp2f(s1[3]);
            u32x4 ppa = {pack_bf16(a0, a1), pack_bf16(a2, a3),
                         pack_bf16(a4, a5), pack_bf16(a6, a7)};
            s16x8 pfA = __builtin_bit_cast(s16x8, ppa);  // x32 A-frag: k=quad*8+i
            oaccA = mfma32(pfA, vf, oaccA);
            daccA = mfma32(pfA, ones, daccA);
            // tile B (same kf/vf — LDS reads amortized)
            f32x4 s2 = mfma16(kf0, qfB, zero4);
            f32x4 s3 = mfma16(kf1, qfB, zero4);
            float b0 = __builtin_amdgcn_exp2f(s2[0]);
            float b1 = __builtin_amdgcn_exp2f(s2[1]);
            float b2 = __builtin_amdgcn_exp2f(s2[2]);
            float b3 = __builtin_amdgcn_exp2f(s2[3]);
            float b4 = __builtin_amdgcn_exp2f(s3[0]);
            float b5 = __builtin_amdgcn_exp2f(s3[1]);
            float b6 = __builtin_amdgcn_exp2f(s3[2]);
            float b7 = __builtin_amdgcn_exp2f(s3[3]);
            u32x4 ppb = {pack_bf16(b0, b1), pack_bf16(b2, b3),
                         pack_bf16(b4, b5), pack_bf16(b6, b7)};
            s16x8 pfB = __builtin_bit_cast(s16x8, ppb);
            oaccB = mfma32(pfB, vf, oaccB);
            daccB = mfma32(pfB, ones, daccB);
        }
        if (c < 7) {                              // land prefetched chunk
            unsigned short* Kn = Ks[(c + 1) & 1];
            unsigned short* Vn = VTs[(c + 1) & 1];
            #pragma unroll
            for (int p = 0; p < 2; p++)
                *(s16x4*)&Kn[(p * 64 + krow) * 20 + kseg] = kst[p];
            *(s16x8*)&Vn[vrow * 136 + vseg] = vst;
        }
    }

    // dacc[r] is the denominator for oacc[r]'s q-row — no shuffles.
    const int orowA = q0 + quad * 4;
    #pragma unroll
    for (int r = 0; r < 4; r++) {
        float rv = oaccA[r] * __builtin_amdgcn_rcpf(daccA[r]);
        O[((size_t)bt * 1024 + orowA + r) * 128 + h * 16 + n16] = f2bf(rv);
    }
    const int orowB = q0 + 16 + quad * 4;
    #pragma unroll
    for (int r = 0; r < 4; r++) {
        float rv = oaccB[r] * __builtin_amdgcn_rcpf(daccB[r]);
        O[((size_t)bt * 1024 + orowB + r) * 128 + h * 16 + n16] = f2bf(rv);
    }
}

// ---------------------------------------------------------------- out proj ---
// X is bf16 (attn output) -> straight b128 staging; W fp32 -> bf16 in LDS.
__global__ __launch_bounds__(256)
void o_proj_kernel(const unsigned short* __restrict__ X, const float* __restrict__ W,
                   const float* __restrict__ bias, float* __restrict__ out)
{
    __shared__ unsigned short Xs[64 * 136];
    __shared__ unsigned short Ws[128 * 136];

    const int t  = threadIdx.x;
    const int m0 = blockIdx.x * 64;

    {
        #pragma unroll
        for (int p = 0; p < 4; p++) {          // 64x128 bf16: 1024 b128 chunks
            int g = p * 256 + t, row = g >> 4, ch = g & 15;
            *(s16x8*)&Xs[row * 136 + ch * 8] =
                *(const s16x8*)(X + (size_t)(m0 + row) * 128 + ch * 8);
        }
        const float4* Wg = (const float4*)W;
        #pragma unroll
        for (int p = 0; p < 16; p++) {
            int g = p * 256 + t;
            float4 vv = Wg[g];
            int row = g >> 5, c4 = g & 31;
            ushort4 d;
            d.x = f2bf(vv.x); d.y = f2bf(vv.y); d.z = f2bf(vv.z); d.w = f2bf(vv.w);
            *(ushort4*)&Ws[row * 136 + c4 * 4] = d;
        }
    }
    __syncthreads();

    const int wave = t >> 6, lane = t & 63, quad = lane >> 4, n16 = lane & 15;
    f32x4 acc[8];
    const f32x4 zero4 = {0.f, 0.f, 0.f, 0.f};
    #pragma unroll
    for (int i = 0; i < 8; i++) acc[i] = zero4;

    #pragma unroll
    for (int ks = 0; ks < 4; ks++) {
        s16x8 a = *(const s16x8*)&Xs[(wave * 16 + n16) * 136 + ks * 32 + quad * 8];
        #pragma unroll
        for (int nt = 0; nt < 8; nt++) {
            s16x8 b = *(const s16x8*)&Ws[(nt * 16 + n16) * 136 + ks * 32 + quad * 8];
            acc[nt] = __builtin_amdgcn_mfma_f32_16x16x32_bf16(a, b, acc[nt], 0, 0, 0);
        }
    }

    const int mrow = m0 + wave * 16 + quad * 4;
    #pragma unroll
    for (int nt = 0; nt < 8; nt++) {
        float bb = bias[nt * 16 + n16];
        #pragma unroll
        for (int r = 0; r < 4; r++)
            out[(size_t)(mrow + r) * 128 + nt * 16 + n16] = acc[nt][r] + bb;
    }
}

// ------------------------------------------------------------------ launch ---
extern "C" void kernel_launch(void* const* d_in, const int* in_sizes, int n_in,
                              void* d_out, int out_size, void* d_ws, size_t ws_size,
                              hipStream_t stream)
{
    const float* query = (const float*)d_in[0];
    const float* key_  = (const float*)d_in[1];
    const float* value = (const float*)d_in[2];
    const float* Wq = (const float*)d_in[3];
    const float* bq = (const float*)d_in[4];
    const float* Wk = (const float*)d_in[5];
    const float* bk = (const float*)d_in[6];
    const float* Wv = (const float*)d_in[7];
    const float* bv = (const float*)d_in[8];
    const float* Wo = (const float*)d_in[9];
    const float* bo = (const float*)d_in[10];
    float* out = (float*)d_out;

    char* ws = (char*)d_ws;
    unsigned short* qb = (unsigned short*)(ws);             // [bt][h][n][hd] bf16
    unsigned short* kb = (unsigned short*)(ws + 6291456);   // [bt][h][n][hd] bf16
    unsigned short* vb = (unsigned short*)(ws + 12582912);  // [bt][h][hd][n] bf16
    unsigned short* Ob = (unsigned short*)(ws + 18874368);  // [bt*1024][128] bf16

    qkv_proj_kernel<<<dim3(384, 3, 1), 256, 0, stream>>>(
        query, key_, value, Wq, Wk, Wv, bq, bk, bv, qb, kb, vb);
    attn_kernel<<<dim3(8, 8, 24), 256, 0, stream>>>(qb, kb, vb, Ob);
    o_proj_kernel<<<dim3(384, 1, 1), 256, 0, stream>>>(Ob, Wo, bo, out);
}

// Round 11
// 143.776 us; speedup vs baseline: 1.0235x; 1.0235x over previous
//
#include <hip/hip_runtime.h>

// AttentionLayer: B=2,T=12,N=1024,D=128,H=8,HD=16
// R11 = R9 (best: single-q-tile attn, 128-j dbuf chunks) + XCD swizzle:
//   attn grid x = head, y = q-block, so all q-blocks sharing one (h,bt)'s K/V
//   land on the same XCD (flat%8 == h) -> K/V fetched once per XCD's L2.
// attn: S^T = K*Q via mfma 16x16x16; K row-permutation folded into the LDS
//   read base. S^T C-layout == 16x16x32 A-frag layout, so PV + denominator
//   are single x32 MFMAs per 32 j (denominator = all-ones B).
// qkv_proj: q/k via LDS-transpose -> coalesced b128; v transposed [bt][h][hd][n].
// softmax scale 1/4*log2(e) folded into stored q (raw exp2 path).

#define DEV __device__ __forceinline__

typedef __attribute__((ext_vector_type(4))) float f32x4;
typedef __attribute__((ext_vector_type(8))) short s16x8;
typedef __attribute__((ext_vector_type(4))) short s16x4;
typedef __attribute__((ext_vector_type(2))) unsigned int u32x2;
typedef __attribute__((ext_vector_type(4))) unsigned int u32x4;

DEV unsigned short f2bf(float f) {          // fp32 -> bf16, round-nearest-even
    unsigned u = __builtin_bit_cast(unsigned, f);
    u = (u + 0x7fffu + ((u >> 16) & 1u)) >> 16;
    return (unsigned short)u;
}

DEV unsigned pack_bf16(float a, float b) {  // {lo=bf16(a), hi=bf16(b)}
#if __has_builtin(__builtin_amdgcn_cvt_pk_bf16_f32)
    typedef __attribute__((ext_vector_type(2))) __bf16 bf16x2;
    bf16x2 t = __builtin_amdgcn_cvt_pk_bf16_f32(a, b);
    return __builtin_bit_cast(unsigned, t);
#else
    // round-half-up: 3 VALU ops; bias cancels in softmax ratio (R4-R10: absmax ok)
    unsigned ua = __builtin_bit_cast(unsigned, a) + 0x8000u;
    unsigned ub = __builtin_bit_cast(unsigned, b) + 0x8000u;
    return __builtin_amdgcn_perm(ub, ua, 0x07060302);  // {ub.hi16, ua.hi16}
#endif
}

DEV f32x4 mfma16(s16x4 a, s16x4 b, f32x4 c) {
#if __has_builtin(__builtin_amdgcn_mfma_f32_16x16x16bf16_1k)
    return __builtin_amdgcn_mfma_f32_16x16x16bf16_1k(a, b, c, 0, 0, 0);
#else
    s16x8 a8 = {a[0], a[1], a[2], a[3], 0, 0, 0, 0};
    s16x8 b8 = {b[0], b[1], b[2], b[3], 0, 0, 0, 0};
    return __builtin_amdgcn_mfma_f32_16x16x32_bf16(a8, b8, c, 0, 0, 0);
#endif
}

DEV f32x4 mfma32(s16x8 a, s16x8 b, f32x4 c) {
    return __builtin_amdgcn_mfma_f32_16x16x32_bf16(a, b, c, 0, 0, 0);
}

// ---------------------------------------------------------------- qkv proj ---
// grid (384, 3): x = 64-row tile of M=24576, y = which of q/k/v.
__global__ __launch_bounds__(256)
void qkv_proj_kernel(const float* __restrict__ xq, const float* __restrict__ xk,
                     const float* __restrict__ xv,
                     const float* __restrict__ Wq, const float* __restrict__ Wk,
                     const float* __restrict__ Wv,
                     const float* __restrict__ bq, const float* __restrict__ bk,
                     const float* __restrict__ bv,
                     unsigned short* __restrict__ oq, unsigned short* __restrict__ ok,
                     unsigned short* __restrict__ ov)
{
    const int z = blockIdx.y;
    const float* X    = (z == 0) ? xq : (z == 1) ? xk : xv;
    const float* W    = (z == 0) ? Wq : (z == 1) ? Wk : Wv;
    const float* bias = (z == 0) ? bq : (z == 1) ? bk : bv;
    unsigned short* out = (z == 0) ? oq : (z == 1) ? ok : ov;
    const float scale = (z == 0) ? 0.25f * 1.44269504088896f : 1.0f;

    __shared__ unsigned short Xs[64 * 136];
    __shared__ unsigned short Ws[128 * 136];

    const int t  = threadIdx.x;
    const int m0 = blockIdx.x * 64;

    {
        const float4* Xg = (const float4*)(X + (size_t)m0 * 128);
        #pragma unroll
        for (int p = 0; p < 8; p++) {
            int g = p * 256 + t;
            float4 vv = Xg[g];
            int row = g >> 5, c4 = g & 31;
            ushort4 d;
            d.x = f2bf(vv.x); d.y = f2bf(vv.y); d.z = f2bf(vv.z); d.w = f2bf(vv.w);
            *(ushort4*)&Xs[row * 136 + c4 * 4] = d;
        }
        const float4* Wg = (const float4*)W;
        #pragma unroll
        for (int p = 0; p < 16; p++) {
            int g = p * 256 + t;
            float4 vv = Wg[g];
            int row = g >> 5, c4 = g & 31;
            ushort4 d;
            d.x = f2bf(vv.x); d.y = f2bf(vv.y); d.z = f2bf(vv.z); d.w = f2bf(vv.w);
            *(ushort4*)&Ws[row * 136 + c4 * 4] = d;
        }
    }
    __syncthreads();

    const int wave = t >> 6, lane = t & 63, quad = lane >> 4, n16 = lane & 15;
    f32x4 acc[8];
    const f32x4 zero4 = {0.f, 0.f, 0.f, 0.f};
    #pragma unroll
    for (int i = 0; i < 8; i++) acc[i] = zero4;

    #pragma unroll
    for (int ks = 0; ks < 4; ks++) {
        s16x8 a = *(const s16x8*)&Xs[(wave * 16 + n16) * 136 + ks * 32 + quad * 8];
        #pragma unroll
        for (int nt = 0; nt < 8; nt++) {
            s16x8 b = *(const s16x8*)&Ws[(nt * 16 + n16) * 136 + ks * 32 + quad * 8];
            acc[nt] = __builtin_amdgcn_mfma_f32_16x16x32_bf16(a, b, acc[nt], 0, 0, 0);
        }
    }

    const int bt    = m0 >> 10;
    const int nbase = (m0 & 1023) + wave * 16 + quad * 4;
    if (z == 2) {
        // V transposed [bt][h][hd][n]: lane holds 4 consecutive n for hd=n16
        #pragma unroll
        for (int nt = 0; nt < 8; nt++) {
            float bb = bias[nt * 16 + n16];
            u32x2 pv = {pack_bf16(acc[nt][0] + bb, acc[nt][1] + bb),
                        pack_bf16(acc[nt][2] + bb, acc[nt][3] + bb)};
            *(u32x2*)&out[((size_t)(bt * 8 + nt) * 16 + n16) * 1024 + nbase] = pv;
        }
    } else {
        // q/k [bt][h][n][hd]: transpose through Xs (done with it) -> coalesced stores
        __syncthreads();
        const int crow = wave * 16 + quad * 4;
        #pragma unroll
        for (int nt = 0; nt < 8; nt++) {
            float bb = bias[nt * 16 + n16];
            #pragma unroll
            for (int r = 0; r < 4; r++)
                Xs[(crow + r) * 136 + nt * 16 + n16] = f2bf((acc[nt][r] + bb) * scale);
        }
        __syncthreads();
        #pragma unroll
        for (int p = 0; p < 4; p++) {
            int g = p * 256 + t, row = g >> 4, ch = g & 15;   // ch*8 = h*16 + seg
            s16x8 val = *(const s16x8*)&Xs[row * 136 + ch * 8];
            *(s16x8*)&out[((size_t)(bt * 8 + (ch >> 1)) * 1024 + (m0 & 1023) + row) * 16
                          + (ch & 1) * 8] = val;
        }
    }
}

// ---------------------------------------------------------------- attention ---
// grid (8, 16, 24): x = head (XCD swizzle: flat%8 == h), y = 64-row q block,
// z = bt.  4 waves, 16 q-rows/wave.  128-j chunks, double-buffered; 18.9 KB LDS.
__global__ __launch_bounds__(256)
void attn_kernel(const unsigned short* __restrict__ q,
                 const unsigned short* __restrict__ k,
                 const unsigned short* __restrict__ vt,
                 unsigned short* __restrict__ O)
{
    __shared__ unsigned short Ks[2][128 * 20];   // K chunk [j][hd], stride 20
    __shared__ unsigned short VTs[2][16 * 136];  // V^T chunk [hd][j], stride 136

    const int t    = threadIdx.x;
    const int lane = t & 63, quad = lane >> 4, n16 = lane & 15;
    const int wave = t >> 6;
    const int h = blockIdx.x, bx = blockIdx.y, bt = blockIdx.z;  // x=h: XCD locality
    const size_t headoff = (size_t)(bt * 8 + h) * 16384;
    const int q0 = bx * 64 + wave * 16;

    // Q B-frag (loop-invariant): B[n=q][k=hd], lane n16 holds hd = quad*4..+3
    s16x4 qf = *(const s16x4*)(q + headoff + (size_t)(q0 + n16) * 16 + quad * 4);

    const f32x4 zero4 = {0.f, 0.f, 0.f, 0.f};
    f32x4 oacc = zero4, dacc = zero4;
    const s16x8 ones = {0x3F80, 0x3F80, 0x3F80, 0x3F80,
                        0x3F80, 0x3F80, 0x3F80, 0x3F80};   // bf16 1.0 x8
    // tile0 lane row j = 8*(n16>>2) + (n16&3)  (permutation folded into base)
    const int krd0 = (8 * (n16 >> 2) + (n16 & 3)) * 20 + quad * 4;
    const int vrd  = n16 * 136 + quad * 8;
    // staging assignments (straight copies)
    const int krow = t >> 2, kseg = (t & 3) * 4;   // K: 2 iters x (64 rows, b64)
    const int vrow = t >> 4, vseg = (t & 15) * 8;  // V: 1 iter  (16 rows, b128)
    const unsigned short* kg = k  + headoff + (size_t)krow * 16 + kseg;
    const unsigned short* vg = vt + headoff + (size_t)vrow * 1024 + vseg;

    // prologue: stage chunk 0 into buffer 0
    #pragma unroll
    for (int p = 0; p < 2; p++)
        *(s16x4*)&Ks[0][(p * 64 + krow) * 20 + kseg] =
            *(const s16x4*)(kg + (size_t)p * 1024);
    *(s16x8*)&VTs[0][vrow * 136 + vseg] = *(const s16x8*)vg;

    #pragma unroll
    for (int c = 0; c < 8; c++) {                 // 8 chunks of 128 j
        __syncthreads();                          // buf[c&1] ready; other free
        s16x4 kst[2];
        s16x8 vst;
        if (c < 7) {                              // issue next chunk's loads now
            #pragma unroll
            for (int p = 0; p < 2; p++)
                kst[p] = *(const s16x4*)(kg + (size_t)((c + 1) * 128 + p * 64) * 16);
            vst = *(const s16x8*)(vg + (c + 1) * 128);
        }
        const unsigned short* Kc = Ks[c & 1];
        const unsigned short* Vc = VTs[c & 1];
        #pragma unroll
        for (int w = 0; w < 4; w++) {             // 4 windows of 32 j
            s16x4 kf0 = *(const s16x4*)&Kc[w * 640 + krd0];        // j=8a+r
            s16x4 kf1 = *(const s16x4*)&Kc[w * 640 + krd0 + 80];   // j=8a+4+r
            f32x4 s0 = mfma16(kf0, qf, zero4);
            f32x4 s1 = mfma16(kf1, qf, zero4);
            float p0 = __builtin_amdgcn_exp2f(s0[0]);
            float p1 = __builtin_amdgcn_exp2f(s0[1]);
            float p2 = __builtin_amdgcn_exp2f(s0[2]);
            float p3 = __builtin_amdgcn_exp2f(s0[3]);
            float p4 = __builtin_amdgcn_exp2f(s1[0]);
            float p5 = __builtin_amdgcn_exp2f(s1[1]);
            float p6 = __builtin_amdgcn_exp2f(s1[2]);
            float p7 = __builtin_amdgcn_exp2f(s1[3]);
            u32x4 pp = {pack_bf16(p0, p1), pack_bf16(p2, p3),
                        pack_bf16(p4, p5), pack_bf16(p6, p7)};
            s16x8 pf = __builtin_bit_cast(s16x8, pp);   // x32 A-frag: k=quad*8+i
            s16x8 vf = *(const s16x8*)&Vc[w * 32 + vrd];
            oacc = mfma32(pf, vf, oacc);          // O: lane hd=n16, q=quad*4+r
            dacc = mfma32(pf, ones, dacc);        // denom, same row mapping
        }
        if (c < 7) {                              // land prefetched chunk
            unsigned short* Kn = Ks[(c + 1) & 1];
            unsigned short* Vn = VTs[(c + 1) & 1];
            #pragma unroll
            for (int p = 0; p < 2; p++)
                *(s16x4*)&Kn[(p * 64 + krow) * 20 + kseg] = kst[p];
            *(s16x8*)&Vn[vrow * 136 + vseg] = vst;
        }
    }

    // dacc[r] is the denominator for oacc[r]'s q-row — no shuffles.
    const int orow = q0 + quad * 4;
    #pragma unroll
    for (int r = 0; r < 4; r++) {
        float rv = oacc[r] * __builtin_amdgcn_rcpf(dacc[r]);
        O[((size_t)bt * 1024 + orow + r) * 128 + h * 16 + n16] = f2bf(rv);
    }
}

// ---------------------------------------------------------------- out proj ---
// X is bf16 (attn output) -> straight b128 staging; W fp32 -> bf16 in LDS.
__global__ __launch_bounds__(256)
void o_proj_kernel(const unsigned short* __restrict__ X, const float* __restrict__ W,
                   const float* __restrict__ bias, float* __restrict__ out)
{
    __shared__ unsigned short Xs[64 * 136];
    __shared__ unsigned short Ws[128 * 136];

    const int t  = threadIdx.x;
    const int m0 = blockIdx.x * 64;

    {
        #pragma unroll
        for (int p = 0; p < 4; p++) {          // 64x128 bf16: 1024 b128 chunks
            int g = p * 256 + t, row = g >> 4, ch = g & 15;
            *(s16x8*)&Xs[row * 136 + ch * 8] =
                *(const s16x8*)(X + (size_t)(m0 + row) * 128 + ch * 8);
        }
        const float4* Wg = (const float4*)W;
        #pragma unroll
        for (int p = 0; p < 16; p++) {
            int g = p * 256 + t;
            float4 vv = Wg[g];
            int row = g >> 5, c4 = g & 31;
            ushort4 d;
            d.x = f2bf(vv.x); d.y = f2bf(vv.y); d.z = f2bf(vv.z); d.w = f2bf(vv.w);
            *(ushort4*)&Ws[row * 136 + c4 * 4] = d;
        }
    }
    __syncthreads();

    const int wave = t >> 6, lane = t & 63, quad = lane >> 4, n16 = lane & 15;
    f32x4 acc[8];
    const f32x4 zero4 = {0.f, 0.f, 0.f, 0.f};
    #pragma unroll
    for (int i = 0; i < 8; i++) acc[i] = zero4;

    #pragma unroll
    for (int ks = 0; ks < 4; ks++) {
        s16x8 a = *(const s16x8*)&Xs[(wave * 16 + n16) * 136 + ks * 32 + quad * 8];
        #pragma unroll
        for (int nt = 0; nt < 8; nt++) {
            s16x8 b = *(const s16x8*)&Ws[(nt * 16 + n16) * 136 + ks * 32 + quad * 8];
            acc[nt] = __builtin_amdgcn_mfma_f32_16x16x32_bf16(a, b, acc[nt], 0, 0, 0);
        }
    }

    const int mrow = m0 + wave * 16 + quad * 4;
    #pragma unroll
    for (int nt = 0; nt < 8; nt++) {
        float bb = bias[nt * 16 + n16];
        #pragma unroll
        for (int r = 0; r < 4; r++)
            out[(size_t)(mrow + r) * 128 + nt * 16 + n16] = acc[nt][r] + bb;
    }
}

// ------------------------------------------------------------------ launch ---
extern "C" void kernel_launch(void* const* d_in, const int* in_sizes, int n_in,
                              void* d_out, int out_size, void* d_ws, size_t ws_size,
                              hipStream_t stream)
{
    const float* query = (const float*)d_in[0];
    const float* key_  = (const float*)d_in[1];
    const float* value = (const float*)d_in[2];
    const float* Wq = (const float*)d_in[3];
    const float* bq = (const float*)d_in[4];
    const float* Wk = (const float*)d_in[5];
    const float* bk = (const float*)d_in[6];
    const float* Wv = (const float*)d_in[7];
    const float* bv = (const float*)d_in[8];
    const float* Wo = (const float*)d_in[9];
    const float* bo = (const float*)d_in[10];
    float* out = (float*)d_out;

    char* ws = (char*)d_ws;
    unsigned short* qb = (unsigned short*)(ws);             // [bt][h][n][hd] bf16
    unsigned short* kb = (unsigned short*)(ws + 6291456);   // [bt][h][n][hd] bf16
    unsigned short* vb = (unsigned short*)(ws + 12582912);  // [bt][h][hd][n] bf16
    unsigned short* Ob = (unsigned short*)(ws + 18874368);  // [bt*1024][128] bf16

    qkv_proj_kernel<<<dim3(384, 3, 1), 256, 0, stream>>>(
        query, key_, value, Wq, Wk, Wv, bq, bk, bv, qb, kb, vb);
    attn_kernel<<<dim3(8, 16, 24), 256, 0, stream>>>(qb, kb, vb, Ob);
    o_proj_kernel<<<dim3(384, 1, 1), 256, 0, stream>>>(Ob, Wo, bo, out);
}